// Round 5
// baseline (40.829 us; speedup 1.0000x reference)
//
#include <hip/hip_runtime.h>
#include <hip/hip_bf16.h>

// Problem constants (fixed by setup_inputs)
#define NB 8
#define G  2048
#define C  512
#define CH 8
#define NM 4
#define HD 10
#define NS 10
#define L1 1022   // (2048-5)/2+1
#define L2 509    // (1022-5)/2+1
#define L3 253    // (509-5)/2+1
#define L4 125    // (253-5)/2+1
#define CPAD 516  // C + 4 pad: bank = (4*H + c) & 31, <=2-way (free); row stride 2064B, 16B-aligned

// ---------------- Kernel 1: RBF density + datarepr -> f32 d_out ----------------
// 256 blocks (NB*32) x 256 threads; thread = (gl 0..31, H 0..7), GT=2 g's per thread.
// LDS holds xc,yc transposed [H][CPAD] so 4 c's load as one ds_read_b128 (broadcast
// across the 8 lanes sharing H; 8 distinct addresses cover all 32 banks once).
__global__ __launch_bounds__(256) void k_density(
    const float* __restrict__ xc, const float* __restrict__ yc,
    const float* __restrict__ xg, const float* __restrict__ logls,
    float* __restrict__ out_den,   // d_out + 0       (nb,G,ch)
    float* __restrict__ out_rep)   // d_out + 131072  (nb,G,ch)
{
    __shared__ __align__(16) float sx[CH * CPAD];
    __shared__ __align__(16) float sy[CH * CPAD];
    const int b   = blockIdx.x >> 5;   // 32 g-tiles per b
    const int gt  = blockIdx.x & 31;
    const int tid = threadIdx.x;

    // transpose-load xc,yc: input layout (c, H), LDS layout [H][c]
    const float* xcb = xc + b * C * CH;
    const float* ycb = yc + b * C * CH;
    for (int i = tid; i < C * CH; i += 256) {
        const int c = i >> 3, H = i & 7;
        sx[H * CPAD + c] = xcb[i];
        sy[H * CPAD + c] = ycb[i];
    }
    __syncthreads();

    const int H  = tid & 7;
    const int gl = tid >> 3;          // 0..31
    const int g0 = gt * 64 + gl;
    const int g1 = g0 + 32;

    const float x0 = xg[(b * G + g0) * CH + H];
    const float x1 = xg[(b * G + g1) * CH + H];
    const float coef = -0.5f * __expf(-2.0f * logls[H]);   // -0.5 / ls^2

    const float4* sxv = (const float4*)(sx + H * CPAD);
    const float4* syv = (const float4*)(sy + H * CPAD);

    float den0 = 0.0f, num0 = 0.0f, den1 = 0.0f, num1 = 0.0f;
    #pragma unroll 2
    for (int c4 = 0; c4 < C / 4; ++c4) {
        const float4 xv = sxv[c4];
        const float4 yv = syv[c4];
        #define STEP(XX, YY)                                            \
        {                                                               \
            const float d0 = x0 - (XX);                                 \
            const float w0 = __expf((d0 * coef) * d0);                  \
            den0 += w0; num0 = fmaf(w0, (YY), num0);                    \
            const float d1 = x1 - (XX);                                 \
            const float w1_ = __expf((d1 * coef) * d1);                 \
            den1 += w1_; num1 = fmaf(w1_, (YY), num1);                  \
        }
        STEP(xv.x, yv.x) STEP(xv.y, yv.y) STEP(xv.z, yv.z) STEP(xv.w, yv.w)
        #undef STEP
    }

    const int o0 = (b * G + g0) * CH + H;
    const int o1 = (b * G + g1) * CH + H;
    out_den[o0] = den0;
    out_rep[o0] = num0 / (den0 + 1e-4f);
    out_den[o1] = den1;
    out_rep[o1] = num1 / (den1 + 1e-4f);
}

// ---------------- conv1: rep (b,g,ch) -> h1 (b,o,l1), relu ----------------
__global__ __launch_bounds__(256) void k_conv1(
    const float* __restrict__ rep, const float* __restrict__ w1,
    const float* __restrict__ b1, float* __restrict__ h1)
{
    const int idx = blockIdx.x * 256 + threadIdx.x;
    if (idx >= NB * HD * L1) return;
    const int l = idx % L1;
    const int t = idx / L1;
    const int o = t % HD;
    const int b = t / HD;

    // 40 contiguous floats of input (64B aligned) and 40 of weights (160B*o aligned)
    const float4* ip = (const float4*)(rep + (b * G + 2 * l) * CH);
    const float4* wp = (const float4*)(w1 + o * CH * 5);
    float4 rv[10], wv[10];
    #pragma unroll
    for (int j = 0; j < 10; ++j) { rv[j] = ip[j]; wv[j] = wp[j]; }
    const float* rf = (const float*)rv;   // linear index k*CH+ci
    const float* wf = (const float*)wv;   // linear index ci*5+k

    float acc = b1[o];
    #pragma unroll
    for (int ci = 0; ci < CH; ++ci)
        #pragma unroll
        for (int k = 0; k < 5; ++k)
            acc = fmaf(rf[k * CH + ci], wf[ci * 5 + k], acc);
    h1[(b * HD + o) * L1 + l] = fmaxf(acc, 0.0f);
}

// ---------------- generic conv (b,cin,lin) -> (b,o,lout), relu ----------------
template<int CIN, int LIN, int LOUT>
__global__ __launch_bounds__(256) void k_conv(
    const float* __restrict__ in, const float* __restrict__ w,
    const float* __restrict__ bias, float* __restrict__ out)
{
    const int idx = blockIdx.x * 256 + threadIdx.x;
    if (idx >= NB * HD * LOUT) return;
    const int l = idx % LOUT;
    const int t = idx / LOUT;
    const int o = t % HD;
    const int b = t / HD;

    const float* ip = in + (b * CIN) * LIN + 2 * l;
    const float* wp = w + o * CIN * 5;
    float acc = bias[o];
    #pragma unroll
    for (int ci = 0; ci < CIN; ++ci)
        #pragma unroll
        for (int k = 0; k < 5; ++k)
            acc = fmaf(ip[ci * LIN + k], wp[ci * 5 + k], acc);
    out[(b * HD + o) * LOUT + l] = fmaxf(acc, 0.0f);
}

// ---------------- head: conv4 + pool + linear + softmax + gumbel ----------------
__global__ __launch_bounds__(256) void k_head(
    const float* __restrict__ h3,   // (NB, HD, L3)
    const float* __restrict__ w4, const float* __restrict__ b4,
    const float* __restrict__ wl, const float* __restrict__ bl,
    const float* __restrict__ unif,
    float* __restrict__ out_mw,   // (NB, CH, NM)
    float* __restrict__ out_ms)   // (NB, NS, CH, NM)
{
    __shared__ float sh4[HD * L4];
    __shared__ float hm[HD];
    __shared__ float ltt[CH * NM];
    const int b   = blockIdx.x;
    const int tid = threadIdx.x;

    // conv4 (no relu): 1250 outputs
    for (int i = tid; i < HD * L4; i += 256) {
        const int l = i % L4, o = i / L4;
        const float* ip = h3 + (b * HD) * L3 + 2 * l;
        const float* wp = w4 + o * HD * 5;
        float acc = b4[o];
        #pragma unroll
        for (int ci = 0; ci < HD; ++ci)
            #pragma unroll
            for (int k = 0; k < 5; ++k)
                acc = fmaf(ip[ci * L3 + k], wp[ci * 5 + k], acc);
        sh4[i] = acc;
    }
    __syncthreads();

    if (tid < HD) {
        float s = 0.0f;
        for (int l = 0; l < L4; ++l) s += sh4[tid * L4 + l];
        hm[tid] = s * (1.0f / (float)L4);
    }
    __syncthreads();

    if (tid < CH * NM) {
        float acc = bl[tid];
        #pragma unroll
        for (int k = 0; k < HD; ++k) acc = fmaf(wl[tid * HD + k], hm[k], acc);
        sh4[tid] = acc;   // raw logits stash
    }
    __syncthreads();

    if (tid < CH) {
        float lv[NM];
        #pragma unroll
        for (int m = 0; m < NM; ++m) lv[m] = sh4[tid * NM + m];
        const float m0 = fmaxf(fmaxf(lv[0], lv[1]), fmaxf(lv[2], lv[3]));
        float e[NM], s = 0.0f;
        #pragma unroll
        for (int m = 0; m < NM; ++m) {
            const float v = (lv[m] - m0) / 0.1f;
            ltt[tid * NM + m] = v;
            e[m] = __expf(v);
            s += e[m];
        }
        #pragma unroll
        for (int m = 0; m < NM; ++m)
            out_mw[(b * CH + tid) * NM + m] = e[m] / s;
    }
    __syncthreads();

    for (int i = tid; i < NS * CH; i += 256) {
        const int c = i % CH, sI = i / CH;
        const float* up = unif + ((b * NS + sI) * CH + c) * NM;
        float hh[NM], mx = -1e30f;
        #pragma unroll
        for (int m = 0; m < NM; ++m) {
            const float gu = -__logf(-__logf(up[m] + 1e-8f));
            hh[m] = (gu + ltt[c * NM + m]) / 0.1f;
            mx = fmaxf(mx, hh[m]);
        }
        float e2[NM], ss = 0.0f;
        #pragma unroll
        for (int m = 0; m < NM; ++m) { e2[m] = __expf(hh[m] - mx); ss += e2[m]; }
        #pragma unroll
        for (int m = 0; m < NM; ++m) {
            float y = e2[m] / ss;
            y = fminf(fmaxf(y, 1e-8f), 1.0f - 1e-8f);
            out_ms[((b * NS + sI) * CH + c) * NM + m] = y;
        }
    }
}

// ---------------- fallback: fully fused net (round-3 proven) ----------------
__global__ __launch_bounds__(256) void k_net_fused(
    const float* __restrict__ rep,
    const float* __restrict__ w1, const float* __restrict__ b1,
    const float* __restrict__ w2, const float* __restrict__ b2,
    const float* __restrict__ w3, const float* __restrict__ b3,
    const float* __restrict__ w4, const float* __restrict__ b4,
    const float* __restrict__ wl, const float* __restrict__ bl,
    const float* __restrict__ unif,
    float* __restrict__ out_mw, float* __restrict__ out_ms)
{
    __shared__ float P[HD * L1];
    __shared__ float Q[HD * L2];
    __shared__ float hm[HD];
    __shared__ float lg[CH * NM];
    __shared__ float ltt[CH * NM];
    const int b   = blockIdx.x;
    const int tid = threadIdx.x;
    const float* repb = rep + b * G * CH;

    for (int i = tid; i < HD * L1; i += 256) {
        const int l = i % L1, o = i / L1;
        float acc = b1[o];
        for (int ci = 0; ci < CH; ++ci)
            #pragma unroll
            for (int k = 0; k < 5; ++k)
                acc = fmaf(repb[(2 * l + k) * CH + ci], w1[(o * CH + ci) * 5 + k], acc);
        P[i] = fmaxf(acc, 0.0f);
    }
    __syncthreads();
    for (int i = tid; i < HD * L2; i += 256) {
        const int l = i % L2, o = i / L2;
        float acc = b2[o];
        for (int ci = 0; ci < HD; ++ci)
            #pragma unroll
            for (int k = 0; k < 5; ++k)
                acc = fmaf(P[ci * L1 + 2 * l + k], w2[(o * HD + ci) * 5 + k], acc);
        Q[i] = fmaxf(acc, 0.0f);
    }
    __syncthreads();
    for (int i = tid; i < HD * L3; i += 256) {
        const int l = i % L3, o = i / L3;
        float acc = b3[o];
        for (int ci = 0; ci < HD; ++ci)
            #pragma unroll
            for (int k = 0; k < 5; ++k)
                acc = fmaf(Q[ci * L2 + 2 * l + k], w3[(o * HD + ci) * 5 + k], acc);
        P[i] = fmaxf(acc, 0.0f);
    }
    __syncthreads();
    for (int i = tid; i < HD * L4; i += 256) {
        const int l = i % L4, o = i / L4;
        float acc = b4[o];
        for (int ci = 0; ci < HD; ++ci)
            #pragma unroll
            for (int k = 0; k < 5; ++k)
                acc = fmaf(P[ci * L3 + 2 * l + k], w4[(o * HD + ci) * 5 + k], acc);
        Q[i] = acc;
    }
    __syncthreads();
    if (tid < HD) {
        float s = 0.0f;
        for (int l = 0; l < L4; ++l) s += Q[tid * L4 + l];
        hm[tid] = s * (1.0f / (float)L4);
    }
    __syncthreads();
    if (tid < CH * NM) {
        float acc = bl[tid];
        #pragma unroll
        for (int k = 0; k < HD; ++k) acc = fmaf(wl[tid * HD + k], hm[k], acc);
        lg[tid] = acc;
    }
    __syncthreads();
    if (tid < CH) {
        float lv[NM];
        #pragma unroll
        for (int m = 0; m < NM; ++m) lv[m] = lg[tid * NM + m];
        const float m0 = fmaxf(fmaxf(lv[0], lv[1]), fmaxf(lv[2], lv[3]));
        float e[NM], s = 0.0f;
        #pragma unroll
        for (int m = 0; m < NM; ++m) {
            const float v = (lv[m] - m0) / 0.1f;
            ltt[tid * NM + m] = v;
            e[m] = __expf(v);
            s += e[m];
        }
        #pragma unroll
        for (int m = 0; m < NM; ++m)
            out_mw[(b * CH + tid) * NM + m] = e[m] / s;
    }
    __syncthreads();
    for (int i = tid; i < NS * CH; i += 256) {
        const int c = i % CH, sI = i / CH;
        const float* up = unif + ((b * NS + sI) * CH + c) * NM;
        float hh[NM], mx = -1e30f;
        #pragma unroll
        for (int m = 0; m < NM; ++m) {
            const float gu = -__logf(-__logf(up[m] + 1e-8f));
            hh[m] = (gu + ltt[c * NM + m]) / 0.1f;
            mx = fmaxf(mx, hh[m]);
        }
        float e2[NM], ss = 0.0f;
        #pragma unroll
        for (int m = 0; m < NM; ++m) { e2[m] = __expf(hh[m] - mx); ss += e2[m]; }
        #pragma unroll
        for (int m = 0; m < NM; ++m) {
            float y = e2[m] / ss;
            y = fminf(fmaxf(y, 1e-8f), 1.0f - 1e-8f);
            out_ms[((b * NS + sI) * CH + c) * NM + m] = y;
        }
    }
}

extern "C" void kernel_launch(void* const* d_in, const int* in_sizes, int n_in,
                              void* d_out, int out_size, void* d_ws, size_t ws_size,
                              hipStream_t stream) {
    const float* xc    = (const float*)d_in[0];
    const float* yc    = (const float*)d_in[1];
    const float* xg    = (const float*)d_in[2];
    const float* logls = (const float*)d_in[3];
    const float* w1    = (const float*)d_in[4];
    const float* b1    = (const float*)d_in[5];
    const float* w2    = (const float*)d_in[6];
    const float* b2    = (const float*)d_in[7];
    const float* w3    = (const float*)d_in[8];
    const float* b3    = (const float*)d_in[9];
    const float* w4    = (const float*)d_in[10];
    const float* b4    = (const float*)d_in[11];
    const float* wl    = (const float*)d_in[12];
    const float* bl    = (const float*)d_in[13];
    const float* unif  = (const float*)d_in[14];

    float* out = (float*)d_out;                 // reference outputs are float32
    float* out_den = out;                       // 131072
    float* out_rep = out + NB * G * CH;         // 131072
    float* out_mw  = out + 2 * NB * G * CH;     // 256
    float* out_ms  = out_mw + NB * CH * NM;     // 2560
    (void)out_size; (void)in_sizes; (void)n_in;

    k_density<<<NB * 32, 256, 0, stream>>>(xc, yc, xg, logls, out_den, out_rep);

    const size_t ws_need = (size_t)(NB * HD * (L1 + L2 + L3)) * sizeof(float); // 570,880 B
    if (ws_size >= ws_need) {
        float* ws_h1 = (float*)d_ws;                 // NB*HD*L1 = 81760
        float* ws_h2 = ws_h1 + NB * HD * L1;         // NB*HD*L2 = 40720
        float* ws_h3 = ws_h2 + NB * HD * L2;         // NB*HD*L3 = 20240

        k_conv1<<<(NB * HD * L1 + 255) / 256, 256, 0, stream>>>(out_rep, w1, b1, ws_h1);
        k_conv<HD, L1, L2><<<(NB * HD * L2 + 255) / 256, 256, 0, stream>>>(ws_h1, w2, b2, ws_h2);
        k_conv<HD, L2, L3><<<(NB * HD * L3 + 255) / 256, 256, 0, stream>>>(ws_h2, w3, b3, ws_h3);
        k_head<<<NB, 256, 0, stream>>>(ws_h3, w4, b4, wl, bl, unif, out_mw, out_ms);
    } else {
        k_net_fused<<<NB, 256, 0, stream>>>(out_rep, w1, b1, w2, b2, w3, b3, w4, b4,
                                            wl, bl, unif, out_mw, out_ms);
    }
}

// Round 6
// 39.315 us; speedup vs baseline: 1.0385x; 1.0385x over previous
//
#include <hip/hip_runtime.h>
#include <hip/hip_bf16.h>

// Problem constants (fixed by setup_inputs)
#define NB 8
#define G  2048
#define C  512
#define CH 8
#define NM 4
#define HD 10
#define NS 10
#define L1 1022   // (2048-5)/2+1
#define L2 509    // (1022-5)/2+1
#define L3 253    // (509-5)/2+1
#define L4 125    // (253-5)/2+1
#define CPAD 516  // C + 4 pad

// ---------------- Kernel 1: RBF density + datarepr -> f32 d_out ----------------
// 256 blocks (NB*32) x 256 threads; thread = (gl 0..31, H 0..7), 2 g's per thread.
// LDS holds xc,yc transposed [H][CPAD] so 4 c's load as one ds_read_b128 broadcast.
__global__ __launch_bounds__(256) void k_density(
    const float* __restrict__ xc, const float* __restrict__ yc,
    const float* __restrict__ xg, const float* __restrict__ logls,
    float* __restrict__ out_den,   // (nb,G,ch)
    float* __restrict__ out_rep)   // (nb,G,ch)
{
    __shared__ __align__(16) float sx[CH * CPAD];
    __shared__ __align__(16) float sy[CH * CPAD];
    const int b   = blockIdx.x >> 5;
    const int gt  = blockIdx.x & 31;
    const int tid = threadIdx.x;

    const float* xcb = xc + b * C * CH;
    const float* ycb = yc + b * C * CH;
    for (int i = tid; i < C * CH; i += 256) {
        const int c = i >> 3, H = i & 7;
        sx[H * CPAD + c] = xcb[i];
        sy[H * CPAD + c] = ycb[i];
    }
    __syncthreads();

    const int H  = tid & 7;
    const int gl = tid >> 3;
    const int g0 = gt * 64 + gl;
    const int g1 = g0 + 32;

    const float x0 = xg[(b * G + g0) * CH + H];
    const float x1 = xg[(b * G + g1) * CH + H];
    // exp(-0.5 d^2/ls^2) == exp2( (-0.5*log2e/ls^2) * d^2 )
    const float coef = -0.72134752044448170f * __expf(-2.0f * logls[H]);

    const float4* sxv = (const float4*)(sx + H * CPAD);
    const float4* syv = (const float4*)(sy + H * CPAD);

    float den0 = 0.0f, num0 = 0.0f, den1 = 0.0f, num1 = 0.0f;
    #pragma unroll 2
    for (int c4 = 0; c4 < C / 4; ++c4) {
        const float4 xv = sxv[c4];
        const float4 yv = syv[c4];
        #define STEP(XX, YY)                                            \
        {                                                               \
            const float d0 = x0 - (XX);                                 \
            const float w0 = exp2f((d0 * coef) * d0);                   \
            den0 += w0; num0 = fmaf(w0, (YY), num0);                    \
            const float d1 = x1 - (XX);                                 \
            const float w1_ = exp2f((d1 * coef) * d1);                  \
            den1 += w1_; num1 = fmaf(w1_, (YY), num1);                  \
        }
        STEP(xv.x, yv.x) STEP(xv.y, yv.y) STEP(xv.z, yv.z) STEP(xv.w, yv.w)
        #undef STEP
    }

    const int o0 = (b * G + g0) * CH + H;
    const int o1 = (b * G + g1) * CH + H;
    out_den[o0] = den0;
    out_rep[o0] = num0 / (den0 + 1e-4f);
    out_den[o1] = den1;
    out_rep[o1] = num1 / (den1 + 1e-4f);
}

// ---------------- Kernel 2: full conv1..4 stencil chain, tiled with halo ---------
// grid = NB*25 blocks x 256 threads. Tile t covers l4 in [5t,5t+5), which needs
// l3 in [10t,10t+13), l2 in [20t,20t+29), l1 in [40t,40t+61), g in [80t,80t+125).
// Everything LDS-resident; writes conv4 output (NB,HD,L4) to ws.
__global__ __launch_bounds__(256) void k_convnet(
    const float* __restrict__ rep,
    const float* __restrict__ w1, const float* __restrict__ b1,
    const float* __restrict__ w2, const float* __restrict__ b2,
    const float* __restrict__ w3, const float* __restrict__ b3,
    const float* __restrict__ w4, const float* __restrict__ b4,
    float* __restrict__ h4out)   // (NB, HD, L4)
{
    const int b   = blockIdx.x / 25;
    const int t   = blockIdx.x % 25;
    const int tid = threadIdx.x;

    __shared__ float sxt[CH * 125];      // rep tile, [ci][125]
    __shared__ float sw1[5 * CH * HD];   // [k][ci][o]
    __shared__ float sw2[5 * HD * HD];
    __shared__ float sw3[5 * HD * HD];
    __shared__ float sw4[5 * HD * HD];
    __shared__ float s1[HD * 61];        // [ci][61]
    __shared__ float s2[HD * 29];
    __shared__ float s3[HD * 13];

    // stage rep tile (1000 floats), coalesced global read
    {
        const float* src = rep + (b * G + 80 * t) * CH;
        for (int i = tid; i < 125 * CH; i += 256) {
            const int gl = i >> 3, ci = i & 7;
            sxt[ci * 125 + gl] = src[i];
        }
    }
    // stage weights, transposed to [k][ci][o]
    for (int i = tid; i < HD * CH * 5; i += 256) {       // 400
        const int o = i / 40, ci = (i / 5) % 8, k = i % 5;
        sw1[(k * CH + ci) * HD + o] = w1[i];
    }
    for (int i = tid; i < HD * HD * 5; i += 256) {       // 500 each
        const int o = i / 50, ci = (i / 5) % 10, k = i % 5;
        const float v2 = w2[i], v3 = w3[i], v4 = w4[i];
        sw2[(k * HD + ci) * HD + o] = v2;
        sw3[(k * HD + ci) * HD + o] = v3;
        sw4[(k * HD + ci) * HD + o] = v4;
    }
    __syncthreads();

    // conv1: 610 outputs (o fast, ll slow) — lanes share ll in groups of 10
    for (int i = tid; i < 61 * HD; i += 256) {
        const int o = i % HD, ll = i / HD;
        float acc = b1[o];
        #pragma unroll
        for (int k = 0; k < 5; ++k)
            #pragma unroll
            for (int ci = 0; ci < CH; ++ci)
                acc = fmaf(sxt[ci * 125 + 2 * ll + k], sw1[(k * CH + ci) * HD + o], acc);
        s1[o * 61 + ll] = fmaxf(acc, 0.0f);
    }
    __syncthreads();

    // conv2: 290 outputs
    for (int i = tid; i < 29 * HD; i += 256) {
        const int o = i % HD, ll = i / HD;
        float acc = b2[o];
        #pragma unroll
        for (int k = 0; k < 5; ++k)
            #pragma unroll
            for (int ci = 0; ci < HD; ++ci)
                acc = fmaf(s1[ci * 61 + 2 * ll + k], sw2[(k * HD + ci) * HD + o], acc);
        s2[o * 29 + ll] = fmaxf(acc, 0.0f);
    }
    __syncthreads();

    // conv3: 130 outputs
    for (int i = tid; i < 13 * HD; i += 256) {
        const int o = i % HD, ll = i / HD;
        float acc = b3[o];
        #pragma unroll
        for (int k = 0; k < 5; ++k)
            #pragma unroll
            for (int ci = 0; ci < HD; ++ci)
                acc = fmaf(s2[ci * 29 + 2 * ll + k], sw3[(k * HD + ci) * HD + o], acc);
        s3[o * 13 + ll] = fmaxf(acc, 0.0f);
    }
    __syncthreads();

    // conv4 (no relu): 50 outputs -> global ws
    for (int i = tid; i < 5 * HD; i += 256) {
        const int o = i % HD, ll = i / HD;
        float acc = b4[o];
        #pragma unroll
        for (int k = 0; k < 5; ++k)
            #pragma unroll
            for (int ci = 0; ci < HD; ++ci)
                acc = fmaf(s3[ci * 13 + 2 * ll + k], sw4[(k * HD + ci) * HD + o], acc);
        h4out[(b * HD + o) * L4 + 5 * t + ll] = acc;
    }
}

// ---------------- Kernel 3: pool + linear + softmax + gumbel ----------------
__global__ __launch_bounds__(256) void k_tail(
    const float* __restrict__ h4,   // (NB, HD, L4)
    const float* __restrict__ wl, const float* __restrict__ bl,
    const float* __restrict__ unif,
    float* __restrict__ out_mw,   // (NB, CH, NM)
    float* __restrict__ out_ms)   // (NB, NS, CH, NM)
{
    const int b   = blockIdx.x;
    const int tid = threadIdx.x;
    __shared__ float red[HD * 25];
    __shared__ float hm[HD];
    __shared__ float lg[CH * NM];
    __shared__ float ltt[CH * NM];

    // partial pool: 250 threads, 5 elements each
    if (tid < HD * 25) {
        const int o = tid / 25, j = tid % 25;
        const float* p = h4 + (b * HD + o) * L4 + j * 5;
        red[tid] = p[0] + p[1] + p[2] + p[3] + p[4];
    }
    __syncthreads();
    if (tid < HD) {
        float s = 0.0f;
        #pragma unroll
        for (int j = 0; j < 25; ++j) s += red[tid * 25 + j];
        hm[tid] = s * (1.0f / (float)L4);
    }
    __syncthreads();
    if (tid < CH * NM) {
        float acc = bl[tid];
        #pragma unroll
        for (int k = 0; k < HD; ++k) acc = fmaf(wl[tid * HD + k], hm[k], acc);
        lg[tid] = acc;
    }
    __syncthreads();
    if (tid < CH) {
        float lv[NM];
        #pragma unroll
        for (int m = 0; m < NM; ++m) lv[m] = lg[tid * NM + m];
        const float m0 = fmaxf(fmaxf(lv[0], lv[1]), fmaxf(lv[2], lv[3]));
        float e[NM], s = 0.0f;
        #pragma unroll
        for (int m = 0; m < NM; ++m) {
            const float v = (lv[m] - m0) / 0.1f;
            ltt[tid * NM + m] = v;
            e[m] = __expf(v);
            s += e[m];
        }
        #pragma unroll
        for (int m = 0; m < NM; ++m)
            out_mw[(b * CH + tid) * NM + m] = e[m] / s;
    }
    __syncthreads();
    if (tid < NS * CH) {
        const int c = tid % CH, sI = tid / CH;
        const float* up = unif + ((b * NS + sI) * CH + c) * NM;
        float hh[NM], mx = -1e30f;
        #pragma unroll
        for (int m = 0; m < NM; ++m) {
            const float gu = -__logf(-__logf(up[m] + 1e-8f));
            hh[m] = (gu + ltt[c * NM + m]) / 0.1f;
            mx = fmaxf(mx, hh[m]);
        }
        float e2[NM], ss = 0.0f;
        #pragma unroll
        for (int m = 0; m < NM; ++m) { e2[m] = __expf(hh[m] - mx); ss += e2[m]; }
        #pragma unroll
        for (int m = 0; m < NM; ++m) {
            float y = e2[m] / ss;
            y = fminf(fmaxf(y, 1e-8f), 1.0f - 1e-8f);
            out_ms[((b * NS + sI) * CH + c) * NM + m] = y;
        }
    }
}

extern "C" void kernel_launch(void* const* d_in, const int* in_sizes, int n_in,
                              void* d_out, int out_size, void* d_ws, size_t ws_size,
                              hipStream_t stream) {
    const float* xc    = (const float*)d_in[0];
    const float* yc    = (const float*)d_in[1];
    const float* xg    = (const float*)d_in[2];
    const float* logls = (const float*)d_in[3];
    const float* w1    = (const float*)d_in[4];
    const float* b1    = (const float*)d_in[5];
    const float* w2    = (const float*)d_in[6];
    const float* b2    = (const float*)d_in[7];
    const float* w3    = (const float*)d_in[8];
    const float* b3    = (const float*)d_in[9];
    const float* w4    = (const float*)d_in[10];
    const float* b4    = (const float*)d_in[11];
    const float* wl    = (const float*)d_in[12];
    const float* bl    = (const float*)d_in[13];
    const float* unif  = (const float*)d_in[14];

    float* out = (float*)d_out;                 // reference outputs are float32
    float* out_den = out;                       // 131072
    float* out_rep = out + NB * G * CH;         // 131072
    float* out_mw  = out + 2 * NB * G * CH;     // 256
    float* out_ms  = out_mw + NB * CH * NM;     // 2560
    (void)out_size; (void)in_sizes; (void)n_in; (void)ws_size;

    float* ws_h4 = (float*)d_ws;                // NB*HD*L4 = 10000 f32 (40 KB)

    k_density<<<NB * 32, 256, 0, stream>>>(xc, yc, xg, logls, out_den, out_rep);

    k_convnet<<<NB * 25, 256, 0, stream>>>(out_rep, w1, b1, w2, b2, w3, b3, w4, b4,
                                           ws_h4);

    k_tail<<<NB, 256, 0, stream>>>(ws_h4, wl, bl, unif, out_mw, out_ms);
}

// Round 7
// 35.211 us; speedup vs baseline: 1.1596x; 1.1166x over previous
//
#include <hip/hip_runtime.h>
#include <hip/hip_bf16.h>

// Problem constants (fixed by setup_inputs)
#define NB 8
#define G  2048
#define C  512
#define CH 8
#define NM 4
#define HD 10
#define NS 10
#define L1 1022   // (2048-5)/2+1
#define L2 509    // (1022-5)/2+1
#define L3 253    // (509-5)/2+1
#define L4 125    // (253-5)/2+1
#define CPAD 516  // C + 4 pad

// ---------------- Kernel 1: RBF density + datarepr -> f32 d_out ----------------
// 512 blocks (NB*64) x 256 threads; thread = (gl 0..31, H 0..7), 1 g per thread.
// 2 blocks/CU -> 2 waves/SIMD for latency hiding. LDS holds xc,yc transposed
// [H][CPAD]; 8 distinct b128 addresses per wave (banks 4H..4H+3), broadcast x8.
__global__ __launch_bounds__(256) void k_density(
    const float* __restrict__ xc, const float* __restrict__ yc,
    const float* __restrict__ xg, const float* __restrict__ logls,
    float* __restrict__ out_den,   // (nb,G,ch)
    float* __restrict__ out_rep)   // (nb,G,ch)
{
    __shared__ __align__(16) float sx[CH * CPAD];
    __shared__ __align__(16) float sy[CH * CPAD];
    const int b   = blockIdx.x >> 6;   // 64 g-tiles per b
    const int gt  = blockIdx.x & 63;
    const int tid = threadIdx.x;

    const float* xcb = xc + b * C * CH;
    const float* ycb = yc + b * C * CH;
    for (int i = tid; i < C * CH; i += 256) {
        const int c = i >> 3, H = i & 7;
        sx[H * CPAD + c] = xcb[i];
        sy[H * CPAD + c] = ycb[i];
    }
    __syncthreads();

    const int H  = tid & 7;
    const int gl = tid >> 3;
    const int g  = gt * 32 + gl;

    const float x = xg[(b * G + g) * CH + H];
    // exp(-0.5 d^2/ls^2) == exp2( (-0.5*log2e/ls^2) * d^2 )
    const float coef = -0.72134752044448170f * __expf(-2.0f * logls[H]);

    const float4* sxv = (const float4*)(sx + H * CPAD);
    const float4* syv = (const float4*)(sy + H * CPAD);

    float den = 0.0f, num = 0.0f;
    #pragma unroll 4
    for (int c4 = 0; c4 < C / 4; ++c4) {
        const float4 xv = sxv[c4];
        const float4 yv = syv[c4];
        #define STEP(XX, YY)                                  \
        {                                                     \
            const float d = x - (XX);                         \
            const float w = exp2f((d * coef) * d);            \
            den += w; num = fmaf(w, (YY), num);               \
        }
        STEP(xv.x, yv.x) STEP(xv.y, yv.y) STEP(xv.z, yv.z) STEP(xv.w, yv.w)
        #undef STEP
    }

    const int o = (b * G + g) * CH + H;
    out_den[o] = den;
    out_rep[o] = num / (den + 1e-4f);
}

// ---------------- Kernel 2: full conv1..4 stencil chain, tiled with halo ---------
// grid = NB*25 blocks x 256 threads. Tile t covers l4 in [5t,5t+5), needing
// l3 [10t,10t+13), l2 [20t,20t+29), l1 [40t,40t+61), g [80t,80t+125).
__global__ __launch_bounds__(256) void k_convnet(
    const float* __restrict__ rep,
    const float* __restrict__ w1, const float* __restrict__ b1,
    const float* __restrict__ w2, const float* __restrict__ b2,
    const float* __restrict__ w3, const float* __restrict__ b3,
    const float* __restrict__ w4, const float* __restrict__ b4,
    float* __restrict__ h4out)   // (NB, HD, L4)
{
    const int b   = blockIdx.x / 25;
    const int t   = blockIdx.x % 25;
    const int tid = threadIdx.x;

    __shared__ float sxt[CH * 125];      // rep tile, [ci][125]
    __shared__ float sw1[5 * CH * HD];   // [k][ci][o]
    __shared__ float sw2[5 * HD * HD];
    __shared__ float sw3[5 * HD * HD];
    __shared__ float sw4[5 * HD * HD];
    __shared__ float s1[HD * 61];        // [ci][61]
    __shared__ float s2[HD * 29];
    __shared__ float s3[HD * 13];

    {
        const float* src = rep + (b * G + 80 * t) * CH;
        for (int i = tid; i < 125 * CH; i += 256) {
            const int gl = i >> 3, ci = i & 7;
            sxt[ci * 125 + gl] = src[i];
        }
    }
    for (int i = tid; i < HD * CH * 5; i += 256) {       // 400
        const int o = i / 40, ci = (i / 5) % 8, k = i % 5;
        sw1[(k * CH + ci) * HD + o] = w1[i];
    }
    for (int i = tid; i < HD * HD * 5; i += 256) {       // 500 each
        const int o = i / 50, ci = (i / 5) % 10, k = i % 5;
        const float v2 = w2[i], v3 = w3[i], v4 = w4[i];
        sw2[(k * HD + ci) * HD + o] = v2;
        sw3[(k * HD + ci) * HD + o] = v3;
        sw4[(k * HD + ci) * HD + o] = v4;
    }
    __syncthreads();

    for (int i = tid; i < 61 * HD; i += 256) {
        const int o = i % HD, ll = i / HD;
        float acc = b1[o];
        #pragma unroll
        for (int k = 0; k < 5; ++k)
            #pragma unroll
            for (int ci = 0; ci < CH; ++ci)
                acc = fmaf(sxt[ci * 125 + 2 * ll + k], sw1[(k * CH + ci) * HD + o], acc);
        s1[o * 61 + ll] = fmaxf(acc, 0.0f);
    }
    __syncthreads();

    for (int i = tid; i < 29 * HD; i += 256) {
        const int o = i % HD, ll = i / HD;
        float acc = b2[o];
        #pragma unroll
        for (int k = 0; k < 5; ++k)
            #pragma unroll
            for (int ci = 0; ci < HD; ++ci)
                acc = fmaf(s1[ci * 61 + 2 * ll + k], sw2[(k * HD + ci) * HD + o], acc);
        s2[o * 29 + ll] = fmaxf(acc, 0.0f);
    }
    __syncthreads();

    for (int i = tid; i < 13 * HD; i += 256) {
        const int o = i % HD, ll = i / HD;
        float acc = b3[o];
        #pragma unroll
        for (int k = 0; k < 5; ++k)
            #pragma unroll
            for (int ci = 0; ci < HD; ++ci)
                acc = fmaf(s2[ci * 29 + 2 * ll + k], sw3[(k * HD + ci) * HD + o], acc);
        s3[o * 13 + ll] = fmaxf(acc, 0.0f);
    }
    __syncthreads();

    for (int i = tid; i < 5 * HD; i += 256) {
        const int o = i % HD, ll = i / HD;
        float acc = b4[o];
        #pragma unroll
        for (int k = 0; k < 5; ++k)
            #pragma unroll
            for (int ci = 0; ci < HD; ++ci)
                acc = fmaf(s3[ci * 13 + 2 * ll + k], sw4[(k * HD + ci) * HD + o], acc);
        h4out[(b * HD + o) * L4 + 5 * t + ll] = acc;
    }
}

// ---------------- Kernel 3: pool + linear + softmax + gumbel ----------------
__global__ __launch_bounds__(256) void k_tail(
    const float* __restrict__ h4,   // (NB, HD, L4)
    const float* __restrict__ wl, const float* __restrict__ bl,
    const float* __restrict__ unif,
    float* __restrict__ out_mw,   // (NB, CH, NM)
    float* __restrict__ out_ms)   // (NB, NS, CH, NM)
{
    const int b   = blockIdx.x;
    const int tid = threadIdx.x;
    __shared__ float red[HD * 25];
    __shared__ float hm[HD];
    __shared__ float lg[CH * NM];
    __shared__ float ltt[CH * NM];

    if (tid < HD * 25) {
        const int o = tid / 25, j = tid % 25;
        const float* p = h4 + (b * HD + o) * L4 + j * 5;
        red[tid] = p[0] + p[1] + p[2] + p[3] + p[4];
    }
    __syncthreads();
    if (tid < HD) {
        float s = 0.0f;
        #pragma unroll
        for (int j = 0; j < 25; ++j) s += red[tid * 25 + j];
        hm[tid] = s * (1.0f / (float)L4);
    }
    __syncthreads();
    if (tid < CH * NM) {
        float acc = bl[tid];
        #pragma unroll
        for (int k = 0; k < HD; ++k) acc = fmaf(wl[tid * HD + k], hm[k], acc);
        lg[tid] = acc;
    }
    __syncthreads();
    if (tid < CH) {
        float lv[NM];
        #pragma unroll
        for (int m = 0; m < NM; ++m) lv[m] = lg[tid * NM + m];
        const float m0 = fmaxf(fmaxf(lv[0], lv[1]), fmaxf(lv[2], lv[3]));
        float e[NM], s = 0.0f;
        #pragma unroll
        for (int m = 0; m < NM; ++m) {
            const float v = (lv[m] - m0) / 0.1f;
            ltt[tid * NM + m] = v;
            e[m] = __expf(v);
            s += e[m];
        }
        #pragma unroll
        for (int m = 0; m < NM; ++m)
            out_mw[(b * CH + tid) * NM + m] = e[m] / s;
    }
    __syncthreads();
    if (tid < NS * CH) {
        const int c = tid % CH, sI = tid / CH;
        const float* up = unif + ((b * NS + sI) * CH + c) * NM;
        float hh[NM], mx = -1e30f;
        #pragma unroll
        for (int m = 0; m < NM; ++m) {
            const float gu = -__logf(-__logf(up[m] + 1e-8f));
            hh[m] = (gu + ltt[c * NM + m]) / 0.1f;
            mx = fmaxf(mx, hh[m]);
        }
        float e2[NM], ss = 0.0f;
        #pragma unroll
        for (int m = 0; m < NM; ++m) { e2[m] = __expf(hh[m] - mx); ss += e2[m]; }
        #pragma unroll
        for (int m = 0; m < NM; ++m) {
            float y = e2[m] / ss;
            y = fminf(fmaxf(y, 1e-8f), 1.0f - 1e-8f);
            out_ms[((b * NS + sI) * CH + c) * NM + m] = y;
        }
    }
}

extern "C" void kernel_launch(void* const* d_in, const int* in_sizes, int n_in,
                              void* d_out, int out_size, void* d_ws, size_t ws_size,
                              hipStream_t stream) {
    const float* xc    = (const float*)d_in[0];
    const float* yc    = (const float*)d_in[1];
    const float* xg    = (const float*)d_in[2];
    const float* logls = (const float*)d_in[3];
    const float* w1    = (const float*)d_in[4];
    const float* b1    = (const float*)d_in[5];
    const float* w2    = (const float*)d_in[6];
    const float* b2    = (const float*)d_in[7];
    const float* w3    = (const float*)d_in[8];
    const float* b3    = (const float*)d_in[9];
    const float* w4    = (const float*)d_in[10];
    const float* b4    = (const float*)d_in[11];
    const float* wl    = (const float*)d_in[12];
    const float* bl    = (const float*)d_in[13];
    const float* unif  = (const float*)d_in[14];

    float* out = (float*)d_out;                 // reference outputs are float32
    float* out_den = out;                       // 131072
    float* out_rep = out + NB * G * CH;         // 131072
    float* out_mw  = out + 2 * NB * G * CH;     // 256
    float* out_ms  = out_mw + NB * CH * NM;     // 2560
    (void)out_size; (void)in_sizes; (void)n_in; (void)ws_size;

    float* ws_h4 = (float*)d_ws;                // NB*HD*L4 = 10000 f32 (40 KB)

    k_density<<<NB * 64, 256, 0, stream>>>(xc, yc, xg, logls, out_den, out_rep);

    k_convnet<<<NB * 25, 256, 0, stream>>>(out_rep, w1, b1, w2, b2, w3, b3, w4, b4,
                                           ws_h4);

    k_tail<<<NB, 256, 0, stream>>>(ws_h4, wl, bl, unif, out_mw, out_ms);
}